// Round 23
// baseline (207.914 us; speedup 1.0000x reference)
//
#include <hip/hip_runtime.h>
#include <hip/hip_bf16.h>
#include <type_traits>

#define B_   4
#define T_   2048
#define D_   1024
#define HQ_  16
#define HKV_ 4
#define HD_  64
#define NQKV_ 1536

typedef __attribute__((ext_vector_type(4))) float f32x4;
typedef __attribute__((ext_vector_type(16))) float f32x16;
typedef _Float16 f16x8 __attribute__((ext_vector_type(8)));
typedef __attribute__((ext_vector_type(8))) unsigned short u16x8;

static __device__ __forceinline__ float h2f(unsigned short u) {
    union { unsigned short u; _Float16 h; } c; c.u = u; return (float)c.h;
}
static __device__ __forceinline__ unsigned short f2h(float f) {
    union { _Float16 h; unsigned short u; } c; c.h = (_Float16)f; return c.u;
}

#define GLL16(gsrc, ldst) \
    __builtin_amdgcn_global_load_lds((const __attribute__((address_space(1))) unsigned int*)(gsrc), \
                                     (__attribute__((address_space(3))) unsigned int*)(ldst), 16, 0, 0)

// ---------------------------------------------------------------- fused cast f32->f16 (x, Wq, Wkv, Wo)
__global__ __launch_bounds__(256) void k_cast_all(const float* __restrict__ x,
                                                  const float* __restrict__ Wq,
                                                  const float* __restrict__ Wkv,
                                                  const float* __restrict__ Wo,
                                                  unsigned short* __restrict__ dst) {
    const int S0 = 2097152;
    const int S1 = S0 + 262144;
    const int S2 = S1 + 131072;
    const int S3 = S2 + 262144;
    int i = blockIdx.x * blockDim.x + threadIdx.x;
    int stride = gridDim.x * blockDim.x;
    for (; i < S3; i += stride) {
        const float* s; int off;
        if (i < S0)      { s = x;   off = i; }
        else if (i < S1) { s = Wq;  off = i - S0; }
        else if (i < S2) { s = Wkv; off = i - S1; }
        else             { s = Wo;  off = i - S2; }
        f32x4 v = ((const f32x4*)s)[off];
        unsigned long long r;
        r  = (unsigned long long)f2h(v.x);
        r |= (unsigned long long)f2h(v.y) << 16;
        r |= (unsigned long long)f2h(v.z) << 32;
        r |= (unsigned long long)f2h(v.w) << 48;
        ((unsigned long long*)dst)[i] = r;
    }
}

// ---------------------------------------------------------------- GEMM  C = A(MxK) * B(NxK)^T
// BK=64; EPI=0: f32 store. EPI=2: fused RoPE + Q/K/V scatter (Q/K stores lane-paired -> u32).
// XCD-aware tile swizzle (nwg%8==0).
template <int EPI>
__global__ __launch_bounds__(256) void k_gemm_bt(const unsigned short* __restrict__ A,
                                                 const unsigned short* __restrict__ Bw,
                                                 void* __restrict__ Cv, int M, int N, int K,
                                                 const float* __restrict__ cosb = nullptr,
                                                 const float* __restrict__ sinb = nullptr,
                                                 unsigned short* __restrict__ qsp = nullptr,
                                                 unsigned short* __restrict__ kbp = nullptr,
                                                 unsigned short* __restrict__ vtp = nullptr) {
    __shared__ __attribute__((aligned(16))) unsigned short As[128 * 64];
    __shared__ __attribute__((aligned(16))) unsigned short Bs[128 * 64];
    const int tid = threadIdx.x;
    const int w = tid >> 6, lane = tid & 63;
    const int gq = lane >> 4, n16 = lane & 15;
    const int lid = blockIdx.y * gridDim.x + blockIdx.x;
    const int cpx = (gridDim.x * gridDim.y) >> 3;
    const int tilid = (lid & 7) * cpx + (lid >> 3);
    const int bx = tilid % gridDim.x, by = tilid / gridDim.x;
    const long gm0 = (long)by * 128, gn0 = (long)bx * 128;
    const int wm = (w >> 1) * 64, wn = (w & 1) * 64;

    f32x4 acc[4][4] = {};

    const int KT = K >> 6;
    const int srow0 = w * 32 + (lane >> 3);
    const int schk = lane & 7;
    unsigned short* alds = &As[w * 2048];
    unsigned short* blds = &Bs[w * 2048];

    auto stage = [&](int kt) {
        const int k0 = kt * 64;
#pragma unroll
        for (int i = 0; i < 4; i++) {
            int row = srow0 + i * 8;
            int chk = schk ^ ((row >> 1) & 3);
            GLL16(A  + (gm0 + row) * K + k0 + chk * 8, alds + i * 512);
            GLL16(Bw + (gn0 + row) * K + k0 + chk * 8, blds + i * 512);
        }
    };

    stage(0);
    for (int kt = 0; kt < KT; ++kt) {
        __syncthreads();
        f16x8 af[4][2], bf[4][2];
#pragma unroll
        for (int mf = 0; mf < 4; mf++) {
            int row = wm + mf * 16 + n16;
            int sw = (row >> 1) & 3;
#pragma unroll
            for (int kk = 0; kk < 2; kk++)
                af[mf][kk] = *(const f16x8*)&As[row * 64 + ((kk * 4 + gq) ^ sw) * 8];
        }
#pragma unroll
        for (int nf = 0; nf < 4; nf++) {
            int row = wn + nf * 16 + n16;
            int sw = (row >> 1) & 3;
#pragma unroll
            for (int kk = 0; kk < 2; kk++)
                bf[nf][kk] = *(const f16x8*)&Bs[row * 64 + ((kk * 4 + gq) ^ sw) * 8];
        }
#pragma unroll
        for (int kk = 0; kk < 2; kk++)
#pragma unroll
            for (int mf = 0; mf < 4; mf++)
#pragma unroll
                for (int nf = 0; nf < 4; nf++)
                    acc[mf][nf] = __builtin_amdgcn_mfma_f32_16x16x32_f16(af[mf][kk], bf[nf][kk], acc[mf][nf], 0, 0, 0);
        __syncthreads();
        if (kt + 1 < KT) stage(kt + 1);
    }

    if constexpr (EPI == 0) {
#pragma unroll
        for (int mf = 0; mf < 4; mf++)
#pragma unroll
            for (int nf = 0; nf < 4; nf++)
#pragma unroll
                for (int q = 0; q < 4; q++) {
                    long r = gm0 + wm + mf * 16 + gq * 4 + q;
                    long c = gn0 + wn + nf * 16 + n16;
                    ((float*)Cv)[r * N + c] = acc[mf][nf][q];
                }
    } else {
        const float ALPHA = 0.125f * 1.44269504088896340736f;
        const int cbase = (int)gn0 + wn;
        const bool isQ = cbase < 1024;
        const int coff = cbase - 1024;
        const bool isV = (!isQ) && ((coff >> 6) & 1);
        const int g = isQ ? 0 : (coff >> 7);
        const bool evenlane = (n16 & 1) == 0;
#pragma unroll
        for (int mf = 0; mf < 4; mf++) {
            long r0 = gm0 + wm + mf * 16 + gq * 4;
            int b = (int)(r0 >> 11);
            int t0 = (int)(r0 & 2047);
#pragma unroll
            for (int nf = 0; nf < 4; nf++) {
                int c = cbase + nf * 16 + n16;
                int d = c & 63;
                if (isQ || !isV) {
                    // lane-paired rope: even lane (even d) computes both (d, d+1) and stores u32.
                    // Math per element identical to scalar path -> bit-identical memory bytes.
                    unsigned short* dst = isQ
                        ? qsp + ((long)(b * HQ_ + (c >> 6)) * T_ + t0) * 64 + d
                        : kbp + ((long)(b * HKV_ + g) * T_ + t0) * 64 + d;
                    const float sc = isQ ? ALPHA : 1.0f;
#pragma unroll
                    for (int q = 0; q < 4; q++) {
                        float v = acc[mf][nf][q];
                        float p = __shfl_xor(v, 1, 64);   // partner's pre-rope value
                        if (evenlane) {
                            float2 cc = *(const float2*)&cosb[(t0 + q) * 64 + d];
                            float2 ss = *(const float2*)&sinb[(t0 + q) * 64 + d];
                            float o0 = (v * cc.x - p * ss.x) * sc;   // even d: v*cos - v_{d+1}*sin
                            float o1 = (p * cc.y + v * ss.y) * sc;   // odd  d: v_{d+1}*cos + v_d*sin
                            unsigned int pk = (unsigned int)f2h(o0) | ((unsigned int)f2h(o1) << 16);
                            *(unsigned int*)&dst[(long)q * 64] = pk;
                        }
                    }
                } else {
                    unsigned long long pk = 0;
#pragma unroll
                    for (int q = 0; q < 4; q++)
                        pk |= (unsigned long long)f2h(acc[mf][nf][q]) << (16 * q);
                    *(unsigned long long*)&vtp[((long)(b * HKV_ + g) * 64 + d) * T_ + t0] = pk;
                }
            }
        }
    }
}

// ---------------------------------------------------------------- flash attention — swapped 32x32, 8-wave blocks
// (r20/r22-verified structure, unchanged)
__global__ __launch_bounds__(512) void k_attn(const unsigned short* __restrict__ qs,
                                              const unsigned short* __restrict__ kb,
                                              const unsigned short* __restrict__ vt,
                                              unsigned short* __restrict__ ao) {
    __shared__ __attribute__((aligned(16))) unsigned short Ks[2][64 * 64];
    __shared__ __attribute__((aligned(16))) unsigned short Vs[2][64 * 64];
    const int tid = threadIdx.x;
    const int w = tid >> 6, lane = tid & 63;
    const int la = lane & 31;
    const bool hi = (lane >> 5) != 0;
    const int bh = blockIdx.y;
    const int b = bh >> 4, h = bh & 15, g = h >> 2;
    const int qt0 = blockIdx.x * 256 + w * 32;

    const unsigned short* Qg = qs + ((long)(b * HQ_ + h) * T_ + qt0 + la) * 64 + (hi ? 8 : 0);
    f16x8 qf[4];
#pragma unroll
    for (int kd = 0; kd < 4; kd++) qf[kd] = *(const f16x8*)&Qg[kd * 16];

    f32x16 oacc[2] = {};
    float rm = -1e30f, rl = 0.f;

    const unsigned short* Kg = kb + (long)(b * HKV_ + g) * T_ * 64;
    const unsigned short* Vg = vt + (long)(b * HKV_ + g) * 64 * T_;

    const int strow = w * 8 + (lane >> 3);
    const int schk = (lane & 7) ^ (lane >> 3);
    const int vrow = tid >> 3;
    const int vc0 = tid & 7;
    const unsigned short* Vrow = Vg + (long)vrow * T_;
    const int vw0 = vrow * 64 + (vc0 ^ (vrow & 7)) * 8;

    const int lx = la & 7;
    int rcb[4];
#pragma unroll
    for (int kd = 0; kd < 4; kd++) rcb[kd] = la * 64 + (((kd * 2 + (int)hi) ^ lx) * 8);

    {
        GLL16(Kg + (long)strow * 64 + schk * 8, &Ks[0][w * 512]);
        u16x8 a = *(const u16x8*)&Vrow[vc0 * 8];
        *(u16x8*)&Vs[0][vw0] = a;
    }

    auto tile = [&](int kt, auto bufc) {
        constexpr int buf = decltype(bufc)::value;
        constexpr int nxt = buf ^ 1;
        __syncthreads();
        const int ktn = (kt < 31) ? kt + 1 : 31;
        GLL16(Kg + ((long)ktn * 64 + strow) * 64 + schk * 8, &Ks[nxt][w * 512]);
        u16x8 nv0 = *(const u16x8*)&Vrow[ktn * 64 + vc0 * 8];
        f16x8 kf[2][4], vf[2][4];
#pragma unroll
        for (int tau = 0; tau < 2; tau++)
#pragma unroll
            for (int kd = 0; kd < 4; kd++)
                kf[tau][kd] = *(const f16x8*)&Ks[buf][tau * 2048 + rcb[kd]];
#pragma unroll
        for (int dt = 0; dt < 2; dt++)
#pragma unroll
            for (int kp = 0; kp < 4; kp++)
                vf[dt][kp] = *(const f16x8*)&Vs[buf][dt * 2048 + rcb[kp]];
        f32x16 sacc[2] = {};
#pragma unroll
        for (int tau = 0; tau < 2; tau++)
#pragma unroll
            for (int kd = 0; kd < 4; kd++)
                sacc[tau] = __builtin_amdgcn_mfma_f32_32x32x16_f16(kf[tau][kd], qf[kd], sacc[tau], 0, 0, 0);
        float t8[8];
#pragma unroll
        for (int r = 0; r < 8; r++)
            t8[r] = fmaxf(fmaxf(sacc[0][r], sacc[0][r + 8]), fmaxf(sacc[1][r], sacc[1][r + 8]));
        float q0 = fmaxf(fmaxf(t8[0], t8[1]), t8[2]);
        float q1 = fmaxf(fmaxf(t8[3], t8[4]), t8[5]);
        float pmax = fmaxf(fmaxf(q0, q1), fmaxf(t8[6], t8[7]));
        if (!__all(pmax - rm <= 8.0f)) {
            float pmaxx = fmaxf(pmax, __shfl_xor(pmax, 32, 64));
            float mnew = fmaxf(rm, pmaxx);
            float corr = __builtin_amdgcn_exp2f(rm - mnew);
            rm = mnew;
            rl *= corr;
#pragma unroll
            for (int dt = 0; dt < 2; dt++) oacc[dt] = oacc[dt] * corr;
        }
        float rs0 = 0.f, rs1 = 0.f;
        unsigned int pka[2][8];
#pragma unroll
        for (int tau = 0; tau < 2; tau++)
#pragma unroll
            for (int r = 0; r < 8; r++) {
                float p0 = __builtin_amdgcn_exp2f(sacc[tau][2 * r]     - rm);
                float p1 = __builtin_amdgcn_exp2f(sacc[tau][2 * r + 1] - rm);
                rs0 += p0; rs1 += p1;
                pka[tau][r] = __builtin_bit_cast(unsigned int, __builtin_amdgcn_cvt_pkrtz(p0, p1));
            }
        rl += rs0 + rs1;
#pragma unroll
        for (int tau = 0; tau < 2; tau++) {
#pragma unroll
            for (int qd = 0; qd < 2; qd++) {
                const int u = qd * 4;
                asm volatile("v_permlane32_swap_b32 %0, %1"
                             : "+v"(pka[tau][u + 0]), "+v"(pka[tau][u + 2]));
                asm volatile("v_permlane32_swap_b32 %0, %1"
                             : "+v"(pka[tau][u + 1]), "+v"(pka[tau][u + 3]));
            }
        }
#pragma unroll
        for (int kp = 0; kp < 4; kp++) {
            const int tau = kp >> 1, u = (kp & 1) * 4;
            union { unsigned int wd[4]; f16x8 v; } pf;
            pf.wd[0] = pka[tau][u + 0];
            pf.wd[1] = pka[tau][u + 1];
            pf.wd[2] = pka[tau][u + 2];
            pf.wd[3] = pka[tau][u + 3];
#pragma unroll
            for (int dt = 0; dt < 2; dt++)
                oacc[dt] = __builtin_amdgcn_mfma_f32_32x32x16_f16(vf[dt][kp], pf.v, oacc[dt], 0, 0, 0);
        }
        *(u16x8*)&Vs[nxt][vw0] = nv0;
    };

    for (int kt2 = 0; kt2 < 32; kt2 += 2) {
        tile(kt2,     std::integral_constant<int, 0>{});
        tile(kt2 + 1, std::integral_constant<int, 1>{});
    }

    float tot = rl + __shfl_xor(rl, 32, 64);
    float inv = 1.0f / tot;
    long t = qt0 + la;
    unsigned short* aor = ao + (long)(b * T_ + t) * D_ + h * 64 + (hi ? 4 : 0);
#pragma unroll
    for (int dt = 0; dt < 2; dt++)
#pragma unroll
        for (int r4 = 0; r4 < 4; r4++) {
            unsigned long long pk;
            pk  = (unsigned long long)f2h(oacc[dt][4 * r4 + 0] * inv);
            pk |= (unsigned long long)f2h(oacc[dt][4 * r4 + 1] * inv) << 16;
            pk |= (unsigned long long)f2h(oacc[dt][4 * r4 + 2] * inv) << 32;
            pk |= (unsigned long long)f2h(oacc[dt][4 * r4 + 3] * inv) << 48;
            *(unsigned long long*)&aor[dt * 32 + 8 * r4] = pk;
        }
}

// ---------------------------------------------------------------- launch
extern "C" void kernel_launch(void* const* d_in, const int* in_sizes, int n_in,
                              void* d_out, int out_size, void* d_ws, size_t ws_size,
                              hipStream_t stream) {
    const float* x    = (const float*)d_in[0];
    const float* cosb = (const float*)d_in[1];
    const float* sinb = (const float*)d_in[2];
    const float* Wq   = (const float*)d_in[3];
    const float* Wkv  = (const float*)d_in[4];
    const float* Wo   = (const float*)d_in[5];
    float* out = (float*)d_out;

    char* ws = (char*)d_ws;
    unsigned short* xb   = (unsigned short*)(ws);              // reused as attnout
    unsigned short* wcat = (unsigned short*)(ws + 16777216);   // [Wq ; Wkv]
    unsigned short* wob  = (unsigned short*)(ws + 19922944);
    unsigned short* qsb  = (unsigned short*)(ws + 47185920);
    unsigned short* vtb  = (unsigned short*)(ws + 63963136);
    unsigned short* kbuf = (unsigned short*)(ws + 68157440);

    k_cast_all<<<2048, 256, 0, stream>>>(x, Wq, Wkv, Wo, xb);

    k_gemm_bt<2><<<dim3(NQKV_ / 128, (B_ * T_) / 128), 256, 0, stream>>>(
        xb, wcat, nullptr, B_ * T_, NQKV_, D_, cosb, sinb, qsb, kbuf, vtb);
    k_attn<<<dim3(T_ / 256, B_ * HQ_), 512, 0, stream>>>(qsb, kbuf, vtb, xb);
    k_gemm_bt<0><<<dim3(D_ / 128, (B_ * T_) / 128), 256, 0, stream>>>(xb, wob, out, B_ * T_, D_, D_);
}

// Round 24
// 186.833 us; speedup vs baseline: 1.1128x; 1.1128x over previous
//
#include <hip/hip_runtime.h>
#include <hip/hip_bf16.h>
#include <type_traits>

#define B_   4
#define T_   2048
#define D_   1024
#define HQ_  16
#define HKV_ 4
#define HD_  64
#define NQKV_ 1536

typedef __attribute__((ext_vector_type(4))) float f32x4;
typedef __attribute__((ext_vector_type(16))) float f32x16;
typedef _Float16 f16x8 __attribute__((ext_vector_type(8)));
typedef __attribute__((ext_vector_type(8))) unsigned short u16x8;

static __device__ __forceinline__ float h2f(unsigned short u) {
    union { unsigned short u; _Float16 h; } c; c.u = u; return (float)c.h;
}
static __device__ __forceinline__ unsigned short f2h(float f) {
    union { _Float16 h; unsigned short u; } c; c.h = (_Float16)f; return c.u;
}

#define GLL16(gsrc, ldst) \
    __builtin_amdgcn_global_load_lds((const __attribute__((address_space(1))) unsigned int*)(gsrc), \
                                     (__attribute__((address_space(3))) unsigned int*)(ldst), 16, 0, 0)

// ---------------------------------------------------------------- fused cast f32->f16 (x, Wq, Wkv, Wo)
__global__ __launch_bounds__(256) void k_cast_all(const float* __restrict__ x,
                                                  const float* __restrict__ Wq,
                                                  const float* __restrict__ Wkv,
                                                  const float* __restrict__ Wo,
                                                  unsigned short* __restrict__ dst) {
    const int S0 = 2097152;
    const int S1 = S0 + 262144;
    const int S2 = S1 + 131072;
    const int S3 = S2 + 262144;
    int i = blockIdx.x * blockDim.x + threadIdx.x;
    int stride = gridDim.x * blockDim.x;
    for (; i < S3; i += stride) {
        const float* s; int off;
        if (i < S0)      { s = x;   off = i; }
        else if (i < S1) { s = Wq;  off = i - S0; }
        else if (i < S2) { s = Wkv; off = i - S1; }
        else             { s = Wo;  off = i - S2; }
        f32x4 v = ((const f32x4*)s)[off];
        unsigned long long r;
        r  = (unsigned long long)f2h(v.x);
        r |= (unsigned long long)f2h(v.y) << 16;
        r |= (unsigned long long)f2h(v.z) << 32;
        r |= (unsigned long long)f2h(v.w) << 48;
        ((unsigned long long*)dst)[i] = r;
    }
}

// ---------------------------------------------------------------- GEMM  C = A(MxK) * B(NxK)^T
// BK=64; EPI=0: f32 store. EPI=2: fused RoPE + Q/K/V scatter. XCD-aware tile swizzle (nwg%8==0).
template <int EPI>
__global__ __launch_bounds__(256) void k_gemm_bt(const unsigned short* __restrict__ A,
                                                 const unsigned short* __restrict__ Bw,
                                                 void* __restrict__ Cv, int M, int N, int K,
                                                 const float* __restrict__ cosb = nullptr,
                                                 const float* __restrict__ sinb = nullptr,
                                                 unsigned short* __restrict__ qsp = nullptr,
                                                 unsigned short* __restrict__ kbp = nullptr,
                                                 unsigned short* __restrict__ vtp = nullptr) {
    __shared__ __attribute__((aligned(16))) unsigned short As[128 * 64];
    __shared__ __attribute__((aligned(16))) unsigned short Bs[128 * 64];
    const int tid = threadIdx.x;
    const int w = tid >> 6, lane = tid & 63;
    const int gq = lane >> 4, n16 = lane & 15;
    const int lid = blockIdx.y * gridDim.x + blockIdx.x;
    const int cpx = (gridDim.x * gridDim.y) >> 3;
    const int tilid = (lid & 7) * cpx + (lid >> 3);
    const int bx = tilid % gridDim.x, by = tilid / gridDim.x;
    const long gm0 = (long)by * 128, gn0 = (long)bx * 128;
    const int wm = (w >> 1) * 64, wn = (w & 1) * 64;

    f32x4 acc[4][4] = {};

    const int KT = K >> 6;
    const int srow0 = w * 32 + (lane >> 3);
    const int schk = lane & 7;
    unsigned short* alds = &As[w * 2048];
    unsigned short* blds = &Bs[w * 2048];

    auto stage = [&](int kt) {
        const int k0 = kt * 64;
#pragma unroll
        for (int i = 0; i < 4; i++) {
            int row = srow0 + i * 8;
            int chk = schk ^ ((row >> 1) & 3);
            GLL16(A  + (gm0 + row) * K + k0 + chk * 8, alds + i * 512);
            GLL16(Bw + (gn0 + row) * K + k0 + chk * 8, blds + i * 512);
        }
    };

    stage(0);
    for (int kt = 0; kt < KT; ++kt) {
        __syncthreads();
        f16x8 af[4][2], bf[4][2];
#pragma unroll
        for (int mf = 0; mf < 4; mf++) {
            int row = wm + mf * 16 + n16;
            int sw = (row >> 1) & 3;
#pragma unroll
            for (int kk = 0; kk < 2; kk++)
                af[mf][kk] = *(const f16x8*)&As[row * 64 + ((kk * 4 + gq) ^ sw) * 8];
        }
#pragma unroll
        for (int nf = 0; nf < 4; nf++) {
            int row = wn + nf * 16 + n16;
            int sw = (row >> 1) & 3;
#pragma unroll
            for (int kk = 0; kk < 2; kk++)
                bf[nf][kk] = *(const f16x8*)&Bs[row * 64 + ((kk * 4 + gq) ^ sw) * 8];
        }
#pragma unroll
        for (int kk = 0; kk < 2; kk++)
#pragma unroll
            for (int mf = 0; mf < 4; mf++)
#pragma unroll
                for (int nf = 0; nf < 4; nf++)
                    acc[mf][nf] = __builtin_amdgcn_mfma_f32_16x16x32_f16(af[mf][kk], bf[nf][kk], acc[mf][nf], 0, 0, 0);
        __syncthreads();
        if (kt + 1 < KT) stage(kt + 1);
    }

    if constexpr (EPI == 0) {
#pragma unroll
        for (int mf = 0; mf < 4; mf++)
#pragma unroll
            for (int nf = 0; nf < 4; nf++)
#pragma unroll
                for (int q = 0; q < 4; q++) {
                    long r = gm0 + wm + mf * 16 + gq * 4 + q;
                    long c = gn0 + wn + nf * 16 + n16;
                    ((float*)Cv)[r * N + c] = acc[mf][nf][q];
                }
    } else {
        const float ALPHA = 0.125f * 1.44269504088896340736f;
        const int cbase = (int)gn0 + wn;
        const bool isQ = cbase < 1024;
        const int coff = cbase - 1024;
        const bool isV = (!isQ) && ((coff >> 6) & 1);
        const int g = isQ ? 0 : (coff >> 7);
#pragma unroll
        for (int mf = 0; mf < 4; mf++) {
            long r0 = gm0 + wm + mf * 16 + gq * 4;
            int b = (int)(r0 >> 11);
            int t0 = (int)(r0 & 2047);
#pragma unroll
            for (int nf = 0; nf < 4; nf++) {
                int c = cbase + nf * 16 + n16;
                int d = c & 63;
                if (isQ || !isV) {
                    unsigned short* dst = isQ
                        ? qsp + ((long)(b * HQ_ + (c >> 6)) * T_ + t0) * 64 + d
                        : kbp + ((long)(b * HKV_ + g) * T_ + t0) * 64 + d;
                    const float sc = isQ ? ALPHA : 1.0f;
#pragma unroll
                    for (int q = 0; q < 4; q++) {
                        float v = acc[mf][nf][q];
                        float p = __shfl_xor(v, 1, 64);
                        float cc = cosb[(t0 + q) * 64 + d];
                        float sn = sinb[(t0 + q) * 64 + d];
                        float o = (d & 1) ? (v * cc + p * sn) : (v * cc - p * sn);
                        dst[(long)q * 64] = f2h(o * sc);
                    }
                } else {
                    unsigned long long pk = 0;
#pragma unroll
                    for (int q = 0; q < 4; q++)
                        pk |= (unsigned long long)f2h(acc[mf][nf][q]) << (16 * q);
                    *(unsigned long long*)&vtp[((long)(b * HKV_ + g) * 64 + d) * T_ + t0] = pk;
                }
            }
        }
    }
}

// ---------------------------------------------------------------- flash attention — swapped 32x32, 8-wave blocks
// T12 P-exchange, operand order per r18/r19/r20 evidence (HW semantics: vdst'=[vdst_lo,src_lo],
// src'=[vdst_hi,src_hi]). In-place asm: swap(pka[u+0], pka[u+2]) -> pka[u+0]=wd[0], pka[u+2]=wd[2].
__global__ __launch_bounds__(512) void k_attn(const unsigned short* __restrict__ qs,
                                              const unsigned short* __restrict__ kb,
                                              const unsigned short* __restrict__ vt,
                                              unsigned short* __restrict__ ao) {
    __shared__ __attribute__((aligned(16))) unsigned short Ks[2][64 * 64];
    __shared__ __attribute__((aligned(16))) unsigned short Vs[2][64 * 64];
    const int tid = threadIdx.x;
    const int w = tid >> 6, lane = tid & 63;
    const int la = lane & 31;
    const bool hi = (lane >> 5) != 0;
    const int bh = blockIdx.y;
    const int b = bh >> 4, h = bh & 15, g = h >> 2;
    const int qt0 = blockIdx.x * 256 + w * 32;

    const unsigned short* Qg = qs + ((long)(b * HQ_ + h) * T_ + qt0 + la) * 64 + (hi ? 8 : 0);
    f16x8 qf[4];
#pragma unroll
    for (int kd = 0; kd < 4; kd++) qf[kd] = *(const f16x8*)&Qg[kd * 16];

    f32x16 oacc[2] = {};
    float rm = -1e30f, rl = 0.f;

    const unsigned short* Kg = kb + (long)(b * HKV_ + g) * T_ * 64;
    const unsigned short* Vg = vt + (long)(b * HKV_ + g) * 64 * T_;

    const int strow = w * 8 + (lane >> 3);
    const int schk = (lane & 7) ^ (lane >> 3);
    const int vrow = tid >> 3;
    const int vc0 = tid & 7;
    const unsigned short* Vrow = Vg + (long)vrow * T_;
    const int vw0 = vrow * 64 + (vc0 ^ (vrow & 7)) * 8;

    const int lx = la & 7;
    int rcb[4];
#pragma unroll
    for (int kd = 0; kd < 4; kd++) rcb[kd] = la * 64 + (((kd * 2 + (int)hi) ^ lx) * 8);

    {
        GLL16(Kg + (long)strow * 64 + schk * 8, &Ks[0][w * 512]);
        u16x8 a = *(const u16x8*)&Vrow[vc0 * 8];
        *(u16x8*)&Vs[0][vw0] = a;
    }

    auto tile = [&](int kt, auto bufc) {
        constexpr int buf = decltype(bufc)::value;
        constexpr int nxt = buf ^ 1;
        __syncthreads();
        const int ktn = (kt < 31) ? kt + 1 : 31;
        GLL16(Kg + ((long)ktn * 64 + strow) * 64 + schk * 8, &Ks[nxt][w * 512]);
        u16x8 nv0 = *(const u16x8*)&Vrow[ktn * 64 + vc0 * 8];
        f16x8 kf[2][4], vf[2][4];
#pragma unroll
        for (int tau = 0; tau < 2; tau++)
#pragma unroll
            for (int kd = 0; kd < 4; kd++)
                kf[tau][kd] = *(const f16x8*)&Ks[buf][tau * 2048 + rcb[kd]];
#pragma unroll
        for (int dt = 0; dt < 2; dt++)
#pragma unroll
            for (int kp = 0; kp < 4; kp++)
                vf[dt][kp] = *(const f16x8*)&Vs[buf][dt * 2048 + rcb[kp]];
        f32x16 sacc[2] = {};
#pragma unroll
        for (int tau = 0; tau < 2; tau++)
#pragma unroll
            for (int kd = 0; kd < 4; kd++)
                sacc[tau] = __builtin_amdgcn_mfma_f32_32x32x16_f16(kf[tau][kd], qf[kd], sacc[tau], 0, 0, 0);
        float t8[8];
#pragma unroll
        for (int r = 0; r < 8; r++)
            t8[r] = fmaxf(fmaxf(sacc[0][r], sacc[0][r + 8]), fmaxf(sacc[1][r], sacc[1][r + 8]));
        float q0 = fmaxf(fmaxf(t8[0], t8[1]), t8[2]);
        float q1 = fmaxf(fmaxf(t8[3], t8[4]), t8[5]);
        float pmax = fmaxf(fmaxf(q0, q1), fmaxf(t8[6], t8[7]));
        if (!__all(pmax - rm <= 8.0f)) {
            float pmaxx = fmaxf(pmax, __shfl_xor(pmax, 32, 64));
            float mnew = fmaxf(rm, pmaxx);
            float corr = __builtin_amdgcn_exp2f(rm - mnew);
            rm = mnew;
            rl *= corr;
#pragma unroll
            for (int dt = 0; dt < 2; dt++) oacc[dt] = oacc[dt] * corr;
        }
        float rs0 = 0.f, rs1 = 0.f;
        unsigned int pka[2][8];
#pragma unroll
        for (int tau = 0; tau < 2; tau++)
#pragma unroll
            for (int r = 0; r < 8; r++) {
                float p0 = __builtin_amdgcn_exp2f(sacc[tau][2 * r]     - rm);
                float p1 = __builtin_amdgcn_exp2f(sacc[tau][2 * r + 1] - rm);
                rs0 += p0; rs1 += p1;
                pka[tau][r] = __builtin_bit_cast(unsigned int, __builtin_amdgcn_cvt_pkrtz(p0, p1));
            }
        rl += rs0 + rs1;
        // ---- P cross-half exchange (r20-verified operand order)
#pragma unroll
        for (int tau = 0; tau < 2; tau++) {
#pragma unroll
            for (int qd = 0; qd < 2; qd++) {
                const int u = qd * 4;
                asm volatile("v_permlane32_swap_b32 %0, %1"
                             : "+v"(pka[tau][u + 0]), "+v"(pka[tau][u + 2]));
                asm volatile("v_permlane32_swap_b32 %0, %1"
                             : "+v"(pka[tau][u + 1]), "+v"(pka[tau][u + 3]));
            }
        }
        // ---- PV: fragment words read directly post-swap
#pragma unroll
        for (int kp = 0; kp < 4; kp++) {
            const int tau = kp >> 1, u = (kp & 1) * 4;
            union { unsigned int wd[4]; f16x8 v; } pf;
            pf.wd[0] = pka[tau][u + 0];
            pf.wd[1] = pka[tau][u + 1];
            pf.wd[2] = pka[tau][u + 2];
            pf.wd[3] = pka[tau][u + 3];
#pragma unroll
            for (int dt = 0; dt < 2; dt++)
                oacc[dt] = __builtin_amdgcn_mfma_f32_32x32x16_f16(vf[dt][kp], pf.v, oacc[dt], 0, 0, 0);
        }
        *(u16x8*)&Vs[nxt][vw0] = nv0;
    };

    for (int kt2 = 0; kt2 < 32; kt2 += 2) {
        tile(kt2,     std::integral_constant<int, 0>{});
        tile(kt2 + 1, std::integral_constant<int, 1>{});
    }

    float tot = rl + __shfl_xor(rl, 32, 64);
    float inv = 1.0f / tot;
    long t = qt0 + la;
    unsigned short* aor = ao + (long)(b * T_ + t) * D_ + h * 64 + (hi ? 4 : 0);
#pragma unroll
    for (int dt = 0; dt < 2; dt++)
#pragma unroll
        for (int r4 = 0; r4 < 4; r4++) {
            unsigned long long pk;
            pk  = (unsigned long long)f2h(oacc[dt][4 * r4 + 0] * inv);
            pk |= (unsigned long long)f2h(oacc[dt][4 * r4 + 1] * inv) << 16;
            pk |= (unsigned long long)f2h(oacc[dt][4 * r4 + 2] * inv) << 32;
            pk |= (unsigned long long)f2h(oacc[dt][4 * r4 + 3] * inv) << 48;
            *(unsigned long long*)&aor[dt * 32 + 8 * r4] = pk;
        }
}

// ---------------------------------------------------------------- launch
extern "C" void kernel_launch(void* const* d_in, const int* in_sizes, int n_in,
                              void* d_out, int out_size, void* d_ws, size_t ws_size,
                              hipStream_t stream) {
    const float* x    = (const float*)d_in[0];
    const float* cosb = (const float*)d_in[1];
    const float* sinb = (const float*)d_in[2];
    const float* Wq   = (const float*)d_in[3];
    const float* Wkv  = (const float*)d_in[4];
    const float* Wo   = (const float*)d_in[5];
    float* out = (float*)d_out;

    char* ws = (char*)d_ws;
    unsigned short* xb   = (unsigned short*)(ws);              // reused as attnout
    unsigned short* wcat = (unsigned short*)(ws + 16777216);   // [Wq ; Wkv]
    unsigned short* wob  = (unsigned short*)(ws + 19922944);
    unsigned short* qsb  = (unsigned short*)(ws + 47185920);
    unsigned short* vtb  = (unsigned short*)(ws + 63963136);
    unsigned short* kbuf = (unsigned short*)(ws + 68157440);

    k_cast_all<<<2048, 256, 0, stream>>>(x, Wq, Wkv, Wo, xb);

    k_gemm_bt<2><<<dim3(NQKV_ / 128, (B_ * T_) / 128), 256, 0, stream>>>(
        xb, wcat, nullptr, B_ * T_, NQKV_, D_, cosb, sinb, qsb, kbuf, vtb);
    k_attn<<<dim3(T_ / 256, B_ * HQ_), 512, 0, stream>>>(qsb, kbuf, vtb, xb);
    k_gemm_bt<0><<<dim3(D_ / 128, (B_ * T_) / 128), 256, 0, stream>>>(xb, wob, out, B_ * T_, D_, D_);
}